// Round 1
// baseline (191.223 us; speedup 1.0000x reference)
//
#include <hip/hip_runtime.h>

#define B 4
#define LQ 512
#define LK 512
#define DQ 256
#define DC 256
#define H 128

// ---------------------------------------------------------------------------
// Kernel 1: projections.
//   qp [B,LQ,H]  = query @ Wq^T + bq
//   cpT[B,H,LK]  = (context @ Wc^T + bc) transposed so kernel 2 reads
//                  cpT[b][h][k] coalesced across k.
// One block per (b,pos); 128 threads, one output h each. Input row staged in
// LDS (coalesced); W row streamed per-thread as float4 (L2-served).
// ---------------------------------------------------------------------------
__global__ __launch_bounds__(128) void ca_proj_kernel(
    const float* __restrict__ query, const float* __restrict__ context,
    const float* __restrict__ Wq, const float* __restrict__ bq,
    const float* __restrict__ Wc, const float* __restrict__ bc,
    float* __restrict__ qp, float* __restrict__ cpT)
{
    __shared__ float row[DQ];
    const int blk = blockIdx.x;
    const int h = threadIdx.x;

    const bool is_q = blk < B * LQ;
    const int idx = is_q ? blk : blk - B * LQ;   // b*L + pos
    const float* __restrict__ src  = is_q ? query : context;
    const float* __restrict__ W    = is_q ? Wq : Wc;
    const float* __restrict__ bias = is_q ? bq : bc;

    const float* r = src + (size_t)idx * DQ;
    row[h]       = r[h];
    row[h + 128] = r[h + 128];
    __syncthreads();

    float acc = bias[h];
    const float4* __restrict__ w4 = (const float4*)(W + (size_t)h * DQ);
    const float4* __restrict__ r4 = (const float4*)row;
#pragma unroll 8
    for (int i = 0; i < DQ / 4; ++i) {
        float4 w = w4[i];
        float4 x = r4[i];
        acc = fmaf(w.x, x.x, acc);
        acc = fmaf(w.y, x.y, acc);
        acc = fmaf(w.z, x.z, acc);
        acc = fmaf(w.w, x.w, acc);
    }

    if (is_q) {
        qp[(size_t)idx * H + h] = acc;
    } else {
        const int b = idx / LK, k = idx % LK;
        cpT[((size_t)b * H + h) * LK + k] = acc;  // transposed (uncoalesced write, 1MB total)
    }
}

// ---------------------------------------------------------------------------
// Kernel 2: scores + softmax + attn@context, one block per (b,q).
// 256 threads, 2 k-values each (LK=512).
// tanh(x) = 1 - 2/(exp(2x)+1)  — saturates correctly at +/-1, no NaN.
// ---------------------------------------------------------------------------
__global__ __launch_bounds__(256) void ca_attn_kernel(
    const float* __restrict__ qp, const float* __restrict__ cpT,
    const float* __restrict__ context,
    const float* __restrict__ Wv, const float* __restrict__ bv,
    float* __restrict__ out)
{
    __shared__ float qv2[H];     // 2*qp[b,q,h]
    __shared__ float wv[H];      // Wv
    __shared__ float attn[LK];
    __shared__ float red[256];

    const int t = threadIdx.x;
    const int bq_idx = blockIdx.x;   // b*LQ + q
    const int b = bq_idx / LQ;

    const float* __restrict__ qrow = qp + (size_t)bq_idx * H;
    if (t < H) {
        qv2[t] = 2.0f * qrow[t];
        wv[t]  = Wv[t];
    }
    __syncthreads();

    const float* __restrict__ cb = cpT + (size_t)b * H * LK;

    // scores: s[k] = sum_h Wv[h] * tanh(qp[h] + 2*cp[k][h])
    float s0 = 0.f, s1 = 0.f;
#pragma unroll 4
    for (int h = 0; h < H; ++h) {
        const float a2 = qv2[h];
        const float w  = wv[h];
        const float c0 = cb[h * LK + t];
        const float c1 = cb[h * LK + t + 256];
        // x2 = 2*(qp + 2*cp) = 2*qp + 4*cp
        const float x0 = fmaf(4.0f, c0, a2);
        const float x1 = fmaf(4.0f, c1, a2);
        const float e0 = __expf(x0);
        const float e1 = __expf(x1);
        const float t0 = 1.0f - 2.0f * __builtin_amdgcn_rcpf(e0 + 1.0f);
        const float t1 = 1.0f - 2.0f * __builtin_amdgcn_rcpf(e1 + 1.0f);
        s0 = fmaf(w, t0, s0);
        s1 = fmaf(w, t1, s1);
    }
    const float bvv = bv[0];
    s0 += bvv;
    s1 += bvv;

    // block softmax over 512 values (2 per thread)
    red[t] = fmaxf(s0, s1);
    __syncthreads();
    for (int off = 128; off > 0; off >>= 1) {
        if (t < off) red[t] = fmaxf(red[t], red[t + off]);
        __syncthreads();
    }
    const float mx = red[0];
    __syncthreads();

    const float p0 = __expf(s0 - mx);
    const float p1 = __expf(s1 - mx);
    red[t] = p0 + p1;
    __syncthreads();
    for (int off = 128; off > 0; off >>= 1) {
        if (t < off) red[t] += red[t + off];
        __syncthreads();
    }
    const float inv = 1.0f / red[0];

    attn[t]       = p0 * inv;
    attn[t + 256] = p1 * inv;
    __syncthreads();

    // out[b,q,d] = sum_k attn[k] * context[b,k,d];  d = t (coalesced)
    const float* __restrict__ ctx = context + (size_t)b * LK * DC;
    float acc = 0.f;
#pragma unroll 8
    for (int k = 0; k < LK; ++k) {
        acc = fmaf(attn[k], ctx[(size_t)k * DC + t], acc);
    }
    out[(size_t)bq_idx * DC + t] = acc;
}

extern "C" void kernel_launch(void* const* d_in, const int* in_sizes, int n_in,
                              void* d_out, int out_size, void* d_ws, size_t ws_size,
                              hipStream_t stream) {
    const float* query   = (const float*)d_in[0];
    const float* context = (const float*)d_in[1];
    const float* Wq = (const float*)d_in[2];
    const float* bq = (const float*)d_in[3];
    const float* Wc = (const float*)d_in[4];
    const float* bc = (const float*)d_in[5];
    const float* Wv = (const float*)d_in[6];
    const float* bv = (const float*)d_in[7];
    float* out = (float*)d_out;

    float* qp  = (float*)d_ws;            // B*LQ*H floats = 1 MB
    float* cpT = qp + (size_t)B * LQ * H; // B*H*LK floats = 1 MB

    ca_proj_kernel<<<B * (LQ + LK), 128, 0, stream>>>(query, context, Wq, bq, Wc, bc, qp, cpT);
    ca_attn_kernel<<<B * LQ, 256, 0, stream>>>(qp, cpT, context, Wv, bv, out);
}

// Round 2
// 120.134 us; speedup vs baseline: 1.5918x; 1.5918x over previous
//
#include <hip/hip_runtime.h>

#define B 4
#define LQ 512
#define LK 512
#define DQ 256
#define DC 256
#define H 128

// ws layout (floats):
//   Eq   [B*LQ][H]        = exp(2*(query@Wq^T + bq))      1 MB
//   EcT  [B][H][LK]       = exp(4*(context@Wc^T + bc))    1 MB  (k-major for coalesced reads)
//   WqT4 [DQ/4][H][4]     transposed+interleaved Wq       128 KB
//   WcT4 [DC/4][H][4]                                     128 KB
//
// tanh(q + 2c) = 1 - 2/(e^{2q} e^{4c} + 1); scores' constant (bv + sum Wv)
// is softmax-shift-invariant and dropped.

__global__ __launch_bounds__(256) void ca_wt_kernel(
    const float* __restrict__ Wq, const float* __restrict__ Wc,
    float* __restrict__ WqT4, float* __restrict__ WcT4)
{
    const int blk = blockIdx.x;
    const bool is_q = blk < 128;
    const float* __restrict__ src = is_q ? Wq : Wc;
    float* __restrict__ dst = is_q ? WqT4 : WcT4;
    const int idx = ((is_q ? blk : blk - 128) << 8) + threadIdx.x; // h*DQ + d
    const int h = idx >> 8;
    const int d = idx & 255;
    dst[(((d >> 2) * H + h) << 2) + (d & 3)] = src[idx];
}

// ---------------------------------------------------------------------------
// Projection: 8 rows/block staged in LDS; thread t -> h = t&127, rowgroup
// t>>7; each thread computes 4 rows x 1 h. W read as coalesced float4 from
// the [d/4][H][4] layout. Applies bias and exp, writes Eq / EcT.
// ---------------------------------------------------------------------------
__global__ __launch_bounds__(256) void ca_proj_kernel(
    const float* __restrict__ query, const float* __restrict__ context,
    const float* __restrict__ WqT4, const float* __restrict__ WcT4,
    const float* __restrict__ bq, const float* __restrict__ bc,
    float* __restrict__ Eq, float* __restrict__ EcT)
{
    __shared__ float rows[8 * DQ];   // 8 KB
    const int t = threadIdx.x;
    const int blk = blockIdx.x;
    const bool is_q = blk < (B * LQ / 8);
    const int row0 = (is_q ? blk : blk - (B * LQ / 8)) * 8;
    const float* __restrict__ src = is_q ? query : context;
    const float4* __restrict__ w4 = (const float4*)(is_q ? WqT4 : WcT4);

    const float* __restrict__ sp = src + (size_t)row0 * DQ;
#pragma unroll
    for (int i = 0; i < 8; ++i) rows[i * 256 + t] = sp[i * 256 + t];
    __syncthreads();

    const int h  = t & 127;
    const int rg = t >> 7;

    float acc0 = 0.f, acc1 = 0.f, acc2 = 0.f, acc3 = 0.f;
#pragma unroll 4
    for (int d4 = 0; d4 < DQ / 4; ++d4) {
        const float4 w  = w4[d4 * H + h];
        const float4 x0 = *(const float4*)&rows[(rg    ) * DQ + d4 * 4];
        const float4 x1 = *(const float4*)&rows[(rg + 2) * DQ + d4 * 4];
        const float4 x2 = *(const float4*)&rows[(rg + 4) * DQ + d4 * 4];
        const float4 x3 = *(const float4*)&rows[(rg + 6) * DQ + d4 * 4];
        acc0 = fmaf(w.x, x0.x, acc0); acc0 = fmaf(w.y, x0.y, acc0);
        acc0 = fmaf(w.z, x0.z, acc0); acc0 = fmaf(w.w, x0.w, acc0);
        acc1 = fmaf(w.x, x1.x, acc1); acc1 = fmaf(w.y, x1.y, acc1);
        acc1 = fmaf(w.z, x1.z, acc1); acc1 = fmaf(w.w, x1.w, acc1);
        acc2 = fmaf(w.x, x2.x, acc2); acc2 = fmaf(w.y, x2.y, acc2);
        acc2 = fmaf(w.z, x2.z, acc2); acc2 = fmaf(w.w, x2.w, acc2);
        acc3 = fmaf(w.x, x3.x, acc3); acc3 = fmaf(w.y, x3.y, acc3);
        acc3 = fmaf(w.z, x3.z, acc3); acc3 = fmaf(w.w, x3.w, acc3);
    }

    const float bias = (is_q ? bq : bc)[h];
    if (is_q) {
        Eq[(size_t)(row0 + rg    ) * H + h] = __expf(2.f * (acc0 + bias));
        Eq[(size_t)(row0 + rg + 2) * H + h] = __expf(2.f * (acc1 + bias));
        Eq[(size_t)(row0 + rg + 4) * H + h] = __expf(2.f * (acc2 + bias));
        Eq[(size_t)(row0 + rg + 6) * H + h] = __expf(2.f * (acc3 + bias));
    } else {
        const float e0 = __expf(4.f * (acc0 + bias));
        const float e1 = __expf(4.f * (acc1 + bias));
        const float e2 = __expf(4.f * (acc2 + bias));
        const float e3 = __expf(4.f * (acc3 + bias));
        int rc = row0 + rg;
        EcT[((size_t)(rc >> 9) * H + h) * LK + (rc & 511)] = e0; rc += 2;
        EcT[((size_t)(rc >> 9) * H + h) * LK + (rc & 511)] = e1; rc += 2;
        EcT[((size_t)(rc >> 9) * H + h) * LK + (rc & 511)] = e2; rc += 2;
        EcT[((size_t)(rc >> 9) * H + h) * LK + (rc & 511)] = e3;
    }
}

// ---------------------------------------------------------------------------
// Attention: one block per 4 q-rows (G=4). grid = 512 -> 2 blocks/CU.
// Score inner loop: r = rcp(Eq*Ec + 1); s~ = -2 * sum_h Wv*r  (shift-invar.)
// Per-wave softmax (wave w owns row w), then attn@context with 4x reuse.
// ---------------------------------------------------------------------------
__global__ __launch_bounds__(256) void ca_attn_kernel(
    const float* __restrict__ Eq, const float* __restrict__ EcT,
    const float* __restrict__ context, const float* __restrict__ Wv,
    float* __restrict__ out)
{
    __shared__ float eqs[4][H];   // 2 KB
    __shared__ float wv[H];
    __shared__ float sc[4][LK];   // 8 KB
    __shared__ float inv[4];

    const int t = threadIdx.x;
    const int bq0 = blockIdx.x * 4;
    const int b = bq0 / LQ;

    if (t < H) {
        wv[t] = Wv[t];
#pragma unroll
        for (int g = 0; g < 4; ++g) eqs[g][t] = Eq[(size_t)(bq0 + g) * H + t];
    }
    __syncthreads();

    const float* __restrict__ ecb = EcT + (size_t)b * H * LK;

    float a00 = 0.f, a01 = 0.f, a10 = 0.f, a11 = 0.f;
    float a20 = 0.f, a21 = 0.f, a30 = 0.f, a31 = 0.f;
#pragma unroll 2
    for (int h4 = 0; h4 < H / 4; ++h4) {
        const float4 w  = *(const float4*)&wv[h4 * 4];
        const float4 e0 = *(const float4*)&eqs[0][h4 * 4];
        const float4 e1 = *(const float4*)&eqs[1][h4 * 4];
        const float4 e2 = *(const float4*)&eqs[2][h4 * 4];
        const float4 e3 = *(const float4*)&eqs[3][h4 * 4];
        const float* __restrict__ ep = ecb + (size_t)h4 * 4 * LK + t;
        const float wl[4] = {w.x, w.y, w.z, w.w};
        const float el0[4] = {e0.x, e0.y, e0.z, e0.w};
        const float el1[4] = {e1.x, e1.y, e1.z, e1.w};
        const float el2[4] = {e2.x, e2.y, e2.z, e2.w};
        const float el3[4] = {e3.x, e3.y, e3.z, e3.w};
#pragma unroll
        for (int c = 0; c < 4; ++c) {
            const float ec0 = ep[c * LK];
            const float ec1 = ep[c * LK + 256];
            const float wc = wl[c];
            float r;
            r = __builtin_amdgcn_rcpf(fmaf(el0[c], ec0, 1.f)); a00 = fmaf(wc, r, a00);
            r = __builtin_amdgcn_rcpf(fmaf(el0[c], ec1, 1.f)); a01 = fmaf(wc, r, a01);
            r = __builtin_amdgcn_rcpf(fmaf(el1[c], ec0, 1.f)); a10 = fmaf(wc, r, a10);
            r = __builtin_amdgcn_rcpf(fmaf(el1[c], ec1, 1.f)); a11 = fmaf(wc, r, a11);
            r = __builtin_amdgcn_rcpf(fmaf(el2[c], ec0, 1.f)); a20 = fmaf(wc, r, a20);
            r = __builtin_amdgcn_rcpf(fmaf(el2[c], ec1, 1.f)); a21 = fmaf(wc, r, a21);
            r = __builtin_amdgcn_rcpf(fmaf(el3[c], ec0, 1.f)); a30 = fmaf(wc, r, a30);
            r = __builtin_amdgcn_rcpf(fmaf(el3[c], ec1, 1.f)); a31 = fmaf(wc, r, a31);
        }
    }

    sc[0][t] = -2.f * a00; sc[0][t + 256] = -2.f * a01;
    sc[1][t] = -2.f * a10; sc[1][t + 256] = -2.f * a11;
    sc[2][t] = -2.f * a20; sc[2][t + 256] = -2.f * a21;
    sc[3][t] = -2.f * a30; sc[3][t + 256] = -2.f * a31;
    __syncthreads();

    // per-wave softmax: wave w owns row w
    {
        const int w_id = t >> 6;
        const int lane = t & 63;
        float v[8];
#pragma unroll
        for (int i = 0; i < 8; ++i) v[i] = sc[w_id][lane + 64 * i];
        float m = v[0];
#pragma unroll
        for (int i = 1; i < 8; ++i) m = fmaxf(m, v[i]);
#pragma unroll
        for (int off = 32; off > 0; off >>= 1) m = fmaxf(m, __shfl_xor(m, off));
        float s = 0.f;
#pragma unroll
        for (int i = 0; i < 8; ++i) { v[i] = __expf(v[i] - m); s += v[i]; }
#pragma unroll
        for (int off = 32; off > 0; off >>= 1) s += __shfl_xor(s, off);
#pragma unroll
        for (int i = 0; i < 8; ++i) sc[w_id][lane + 64 * i] = v[i];
        if (lane == 0) inv[w_id] = 1.f / s;
    }
    __syncthreads();

    // epilogue: out[g][d=t] = inv[g] * sum_k p[g][k] * ctx[k][d]
    const float* __restrict__ ctx = context + (size_t)b * LK * DC + t;
    float o0 = 0.f, o1 = 0.f, o2 = 0.f, o3 = 0.f;
#pragma unroll 2
    for (int k = 0; k < LK; k += 4) {
        const float4 p0 = *(const float4*)&sc[0][k];
        const float4 p1 = *(const float4*)&sc[1][k];
        const float4 p2 = *(const float4*)&sc[2][k];
        const float4 p3 = *(const float4*)&sc[3][k];
        const float pl0[4] = {p0.x, p0.y, p0.z, p0.w};
        const float pl1[4] = {p1.x, p1.y, p1.z, p1.w};
        const float pl2[4] = {p2.x, p2.y, p2.z, p2.w};
        const float pl3[4] = {p3.x, p3.y, p3.z, p3.w};
#pragma unroll
        for (int c = 0; c < 4; ++c) {
            const float cv = ctx[(size_t)(k + c) * DC];
            o0 = fmaf(pl0[c], cv, o0);
            o1 = fmaf(pl1[c], cv, o1);
            o2 = fmaf(pl2[c], cv, o2);
            o3 = fmaf(pl3[c], cv, o3);
        }
    }
    out[(size_t)(bq0 + 0) * DC + t] = o0 * inv[0];
    out[(size_t)(bq0 + 1) * DC + t] = o1 * inv[1];
    out[(size_t)(bq0 + 2) * DC + t] = o2 * inv[2];
    out[(size_t)(bq0 + 3) * DC + t] = o3 * inv[3];
}

extern "C" void kernel_launch(void* const* d_in, const int* in_sizes, int n_in,
                              void* d_out, int out_size, void* d_ws, size_t ws_size,
                              hipStream_t stream) {
    const float* query   = (const float*)d_in[0];
    const float* context = (const float*)d_in[1];
    const float* Wq = (const float*)d_in[2];
    const float* bq = (const float*)d_in[3];
    const float* Wc = (const float*)d_in[4];
    const float* bc = (const float*)d_in[5];
    const float* Wv = (const float*)d_in[6];
    const float* bv = (const float*)d_in[7];  // dropped: softmax shift-invariant
    (void)bv;
    float* out = (float*)d_out;

    float* Eq   = (float*)d_ws;                     // 262144 floats
    float* EcT  = Eq  + (size_t)B * LQ * H;         // 262144 floats
    float* WqT4 = EcT + (size_t)B * H * LK;         // 32768 floats
    float* WcT4 = WqT4 + (size_t)H * DQ;            // 32768 floats

    ca_wt_kernel<<<256, 256, 0, stream>>>(Wq, Wc, WqT4, WcT4);
    ca_proj_kernel<<<B * (LQ + LK) / 8, 256, 0, stream>>>(
        query, context, WqT4, WcT4, bq, bc, Eq, EcT);
    ca_attn_kernel<<<B * LQ / 4, 256, 0, stream>>>(Eq, EcT, context, Wv, out);
}

// Round 3
// 112.558 us; speedup vs baseline: 1.6989x; 1.0673x over previous
//
#include <hip/hip_runtime.h>

#define B 4
#define LQ 512
#define LK 512
#define DQ 256
#define DC 256
#define H 128

// ws layout (floats):
//   Eq   [B*LQ][H]    = exp(2*(query@Wq^T + bq))    1 MB
//   EcT  [B][H][LK]   = exp(4*(context@Wc^T + bc))  1 MB (k-major)
//   WqT4 [DQ/4][H][4] transposed Wq                 128 KB
//   WcT4 [DC/4][H][4] transposed Wc                 128 KB
//
// tanh(q + 2c) = 1 - 2/(e^{2q} e^{4c} + 1). The constant (bv + sum_h Wv)
// is softmax-shift-invariant and dropped.

__global__ __launch_bounds__(256) void ca_wt_kernel(
    const float* __restrict__ Wq, const float* __restrict__ Wc,
    float* __restrict__ WqT4, float* __restrict__ WcT4)
{
    const int blk = blockIdx.x;
    const bool is_q = blk < 128;
    const float* __restrict__ src = is_q ? Wq : Wc;
    float* __restrict__ dst = is_q ? WqT4 : WcT4;
    const int idx = ((is_q ? blk : blk - 128) << 8) + threadIdx.x; // h*DQ + d
    const int h = idx >> 8;
    const int d = idx & 255;
    dst[(((d >> 2) * H + h) << 2) + (d & 3)] = src[idx];
}

// ---------------------------------------------------------------------------
// Projection, LDS-free: 8 rows/block, 256 threads. h = t&127; row group
// rg = t>>7 (wave-uniform, forced scalar via readfirstlane) -> x rows are
// s_load'ed through the scalar cache; W float4 loads are coalesced.
// ---------------------------------------------------------------------------
__global__ __launch_bounds__(256, 4) void ca_proj_kernel(
    const float* __restrict__ query, const float* __restrict__ context,
    const float* __restrict__ WqT4, const float* __restrict__ WcT4,
    const float* __restrict__ bq, const float* __restrict__ bc,
    float* __restrict__ Eq, float* __restrict__ EcT)
{
    const int t = threadIdx.x;
    const int blk = blockIdx.x;
    const bool is_q = blk < (B * LQ / 8);
    const int row0 = (is_q ? blk : blk - (B * LQ / 8)) * 8;
    const float* __restrict__ src = is_q ? query : context;
    const float4* __restrict__ w4 = (const float4*)(is_q ? WqT4 : WcT4);

    const int h = t & 127;
    const int rg = __builtin_amdgcn_readfirstlane(t >> 7); // wave-uniform 0/1

    const float* __restrict__ x0p = src + (size_t)(row0 + rg    ) * DQ;
    const float* __restrict__ x1p = src + (size_t)(row0 + rg + 2) * DQ;
    const float* __restrict__ x2p = src + (size_t)(row0 + rg + 4) * DQ;
    const float* __restrict__ x3p = src + (size_t)(row0 + rg + 6) * DQ;

    float acc0 = 0.f, acc1 = 0.f, acc2 = 0.f, acc3 = 0.f;
#pragma unroll 4
    for (int d4 = 0; d4 < DQ / 4; ++d4) {
        const float4 w  = w4[d4 * H + h];
        const float4 x0 = *(const float4*)(x0p + d4 * 4);
        const float4 x1 = *(const float4*)(x1p + d4 * 4);
        const float4 x2 = *(const float4*)(x2p + d4 * 4);
        const float4 x3 = *(const float4*)(x3p + d4 * 4);
        acc0 = fmaf(w.x, x0.x, acc0); acc0 = fmaf(w.y, x0.y, acc0);
        acc0 = fmaf(w.z, x0.z, acc0); acc0 = fmaf(w.w, x0.w, acc0);
        acc1 = fmaf(w.x, x1.x, acc1); acc1 = fmaf(w.y, x1.y, acc1);
        acc1 = fmaf(w.z, x1.z, acc1); acc1 = fmaf(w.w, x1.w, acc1);
        acc2 = fmaf(w.x, x2.x, acc2); acc2 = fmaf(w.y, x2.y, acc2);
        acc2 = fmaf(w.z, x2.z, acc2); acc2 = fmaf(w.w, x2.w, acc2);
        acc3 = fmaf(w.x, x3.x, acc3); acc3 = fmaf(w.y, x3.y, acc3);
        acc3 = fmaf(w.z, x3.z, acc3); acc3 = fmaf(w.w, x3.w, acc3);
    }

    const float bias = (is_q ? bq : bc)[h];
    if (is_q) {
        Eq[(size_t)(row0 + rg    ) * H + h] = __expf(2.f * (acc0 + bias));
        Eq[(size_t)(row0 + rg + 2) * H + h] = __expf(2.f * (acc1 + bias));
        Eq[(size_t)(row0 + rg + 4) * H + h] = __expf(2.f * (acc2 + bias));
        Eq[(size_t)(row0 + rg + 6) * H + h] = __expf(2.f * (acc3 + bias));
    } else {
        const float e0 = __expf(4.f * (acc0 + bias));
        const float e1 = __expf(4.f * (acc1 + bias));
        const float e2 = __expf(4.f * (acc2 + bias));
        const float e3 = __expf(4.f * (acc3 + bias));
        int rc = row0 + rg;
        EcT[((size_t)(rc >> 9) * H + h) * LK + (rc & 511)] = e0; rc += 2;
        EcT[((size_t)(rc >> 9) * H + h) * LK + (rc & 511)] = e1; rc += 2;
        EcT[((size_t)(rc >> 9) * H + h) * LK + (rc & 511)] = e2; rc += 2;
        EcT[((size_t)(rc >> 9) * H + h) * LK + (rc & 511)] = e3;
    }
}

// ---------------------------------------------------------------------------
// Attention: 512 threads (8 waves), 4 q-rows per block, grid = 512.
// Score: thread t owns k=t; Eq/Wv via uniform scalar loads; 1 rcp + 2 fma
// per (g,h). Softmax: waves 0-3 own rows 0-3. Epilogue: wave w owns k-slice
// [64w,64w+64), float4 ctx loads, LDS partial reduce over the 8 slices.
// ---------------------------------------------------------------------------
__global__ __launch_bounds__(512, 4) void ca_attn_kernel(
    const float* __restrict__ Eq, const float* __restrict__ EcT,
    const float* __restrict__ context, const float* __restrict__ Wv,
    float* __restrict__ out)
{
    __shared__ float sc[4][LK];        // 8 KB: scores, then unnormalized p
    __shared__ float part[8][4][DC];   // 32 KB: epilogue partials
    __shared__ float inv[4];

    const int t = threadIdx.x;
    const int bq0 = blockIdx.x * 4;
    const int b = bq0 / LQ;

    const float* __restrict__ ecb = EcT + (size_t)b * H * LK;
    const float* __restrict__ eqb = Eq + (size_t)bq0 * H;

    // ---- scores: s[g][k=t] = -2 * sum_h Wv[h] * rcp(Eq[g][h]*Ec[h][k] + 1)
    float a[4] = {0.f, 0.f, 0.f, 0.f};
#pragma unroll 4
    for (int h4 = 0; h4 < H / 4; ++h4) {
        const float4 wv = *(const float4*)(Wv  + h4 * 4);          // s_load
        float4 q[4];
#pragma unroll
        for (int g = 0; g < 4; ++g)
            q[g] = *(const float4*)(eqb + g * H + h4 * 4);         // s_load
        const float* __restrict__ ep = ecb + (size_t)h4 * 4 * LK + t;
        const float e0 = ep[0 * LK];
        const float e1 = ep[1 * LK];
        const float e2 = ep[2 * LK];
        const float e3 = ep[3 * LK];
        float r;
#pragma unroll
        for (int g = 0; g < 4; ++g) {
            r = __builtin_amdgcn_rcpf(fmaf(q[g].x, e0, 1.f)); a[g] = fmaf(wv.x, r, a[g]);
            r = __builtin_amdgcn_rcpf(fmaf(q[g].y, e1, 1.f)); a[g] = fmaf(wv.y, r, a[g]);
            r = __builtin_amdgcn_rcpf(fmaf(q[g].z, e2, 1.f)); a[g] = fmaf(wv.z, r, a[g]);
            r = __builtin_amdgcn_rcpf(fmaf(q[g].w, e3, 1.f)); a[g] = fmaf(wv.w, r, a[g]);
        }
    }
#pragma unroll
    for (int g = 0; g < 4; ++g) sc[g][t] = -2.f * a[g];
    __syncthreads();

    // ---- softmax: wave w (<4) owns row w; store raw exp, inv holds 1/sum
    {
        const int w_id = t >> 6;
        const int lane = t & 63;
        if (w_id < 4) {
            float v[8];
#pragma unroll
            for (int i = 0; i < 8; ++i) v[i] = sc[w_id][lane + 64 * i];
            float m = v[0];
#pragma unroll
            for (int i = 1; i < 8; ++i) m = fmaxf(m, v[i]);
#pragma unroll
            for (int off = 32; off > 0; off >>= 1) m = fmaxf(m, __shfl_xor(m, off));
            float s = 0.f;
#pragma unroll
            for (int i = 0; i < 8; ++i) { v[i] = __expf(v[i] - m); s += v[i]; }
#pragma unroll
            for (int off = 32; off > 0; off >>= 1) s += __shfl_xor(s, off);
#pragma unroll
            for (int i = 0; i < 8; ++i) sc[w_id][lane + 64 * i] = v[i];
            if (lane == 0) inv[w_id] = 1.f / s;
        }
    }
    __syncthreads();

    // ---- epilogue: part[w][g][d] = sum_{k in slice w} p[g][k]*ctx[k][d]
    {
        const int kh = t >> 6;            // wave id = k-slice
        const int d4 = (t & 63) * 4;
        const float* __restrict__ ctx = context + (size_t)b * LK * DC + d4;
        float4 o[4];
#pragma unroll
        for (int g = 0; g < 4; ++g) o[g] = make_float4(0.f, 0.f, 0.f, 0.f);
#pragma unroll 2
        for (int j = 0; j < 16; ++j) {    // 4 k per iter
            const int k = kh * 64 + j * 4;
            float4 p[4];
#pragma unroll
            for (int g = 0; g < 4; ++g) p[g] = *(const float4*)&sc[g][k];
#pragma unroll
            for (int c = 0; c < 4; ++c) {
                const float4 cv = *(const float4*)(ctx + (size_t)(k + c) * DC);
                const float pc[4] = {p[0].x, p[1].x, p[2].x, p[3].x};
                const float pd[4] = {p[0].y, p[1].y, p[2].y, p[3].y};
                const float pe[4] = {p[0].z, p[1].z, p[2].z, p[3].z};
                const float pf[4] = {p[0].w, p[1].w, p[2].w, p[3].w};
                const float* sel = (c == 0) ? pc : (c == 1) ? pd : (c == 2) ? pe : pf;
#pragma unroll
                for (int g = 0; g < 4; ++g) {
                    o[g].x = fmaf(sel[g], cv.x, o[g].x);
                    o[g].y = fmaf(sel[g], cv.y, o[g].y);
                    o[g].z = fmaf(sel[g], cv.z, o[g].z);
                    o[g].w = fmaf(sel[g], cv.w, o[g].w);
                }
            }
        }
#pragma unroll
        for (int g = 0; g < 4; ++g)
            *(float4*)&part[kh][g][d4] = o[g];
    }
    __syncthreads();

    // ---- combine the 8 k-slices, scale by 1/sum, store
    if (t < 256) {
#pragma unroll
        for (int g = 0; g < 4; ++g) {
            float s = 0.f;
#pragma unroll
            for (int kh = 0; kh < 8; ++kh) s += part[kh][g][t];
            out[(size_t)(bq0 + g) * DC + t] = s * inv[g];
        }
    }
}

extern "C" void kernel_launch(void* const* d_in, const int* in_sizes, int n_in,
                              void* d_out, int out_size, void* d_ws, size_t ws_size,
                              hipStream_t stream) {
    const float* query   = (const float*)d_in[0];
    const float* context = (const float*)d_in[1];
    const float* Wq = (const float*)d_in[2];
    const float* bq = (const float*)d_in[3];
    const float* Wc = (const float*)d_in[4];
    const float* bc = (const float*)d_in[5];
    const float* Wv = (const float*)d_in[6];
    const float* bv = (const float*)d_in[7];  // dropped: softmax shift-invariant
    (void)bv;
    float* out = (float*)d_out;

    float* Eq   = (float*)d_ws;                     // 262144 floats
    float* EcT  = Eq  + (size_t)B * LQ * H;         // 262144 floats
    float* WqT4 = EcT + (size_t)B * H * LK;         // 32768 floats
    float* WcT4 = WqT4 + (size_t)H * DQ;            // 32768 floats

    ca_wt_kernel<<<256, 256, 0, stream>>>(Wq, Wc, WqT4, WcT4);
    ca_proj_kernel<<<B * (LQ + LK) / 8, 256, 0, stream>>>(
        query, context, WqT4, WcT4, bq, bc, Eq, EcT);
    ca_attn_kernel<<<B * LQ / 4, 512, 0, stream>>>(Eq, EcT, context, Wv, out);
}

// Round 4
// 110.321 us; speedup vs baseline: 1.7333x; 1.0203x over previous
//
#include <hip/hip_runtime.h>

#define B 4
#define LQ 512
#define LK 512
#define DQ 256
#define DC 256
#define H 128

// ws layout (floats):
//   Eq   [B*LQ][H]        = exp(2*(query@Wq^T + bq))            1 MB
//   EcT4 [B][H/4][LK][4]  = exp(4*(context@Wc^T + bc)), h-int.  1 MB
//   WqT4 [DQ/4][H][4]     transposed Wq                         128 KB
//   WcT4 [DC/4][H][4]     transposed Wc                         128 KB
//
// tanh(q + 2c) = 1 - 2/(e^{2q} e^{4c} + 1). The constant (bv + sum_h Wv)
// is softmax-shift-invariant and dropped. Reciprocal pairing:
//   w0/A + w1/B = (w0*B + w1*A) / (A*B)   -> one rcp per two h.

__global__ __launch_bounds__(256) void ca_wt_kernel(
    const float* __restrict__ Wq, const float* __restrict__ Wc,
    float* __restrict__ WqT4, float* __restrict__ WcT4)
{
    const int blk = blockIdx.x;
    const bool is_q = blk < 128;
    const float* __restrict__ src = is_q ? Wq : Wc;
    float* __restrict__ dst = is_q ? WqT4 : WcT4;
    const int idx = ((is_q ? blk : blk - 128) << 8) + threadIdx.x; // h*DQ + d
    const int h = idx >> 8;
    const int d = idx & 255;
    dst[(((d >> 2) * H + h) << 2) + (d & 3)] = src[idx];
}

// ---------------------------------------------------------------------------
// Projection, LDS-free: 16 rows/block, 512 threads. h = t&127, row group
// rg = t>>7 in {0..3} (wave-uniform via readfirstlane -> x rows s_load'ed).
// Each thread computes 4 rows (rg, rg+4, rg+8, rg+12) x 1 h.
// ---------------------------------------------------------------------------
__global__ __launch_bounds__(512, 4) void ca_proj_kernel(
    const float* __restrict__ query, const float* __restrict__ context,
    const float* __restrict__ WqT4, const float* __restrict__ WcT4,
    const float* __restrict__ bq, const float* __restrict__ bc,
    float* __restrict__ Eq, float* __restrict__ EcT4)
{
    const int t = threadIdx.x;
    const int blk = blockIdx.x;
    const bool is_q = blk < (B * LQ / 16);
    const int row0 = (is_q ? blk : blk - (B * LQ / 16)) * 16;
    const float* __restrict__ src = is_q ? query : context;
    const float4* __restrict__ w4 = (const float4*)(is_q ? WqT4 : WcT4);

    const int h = t & 127;
    const int rg = __builtin_amdgcn_readfirstlane(t >> 7); // wave-uniform 0..3

    const float* __restrict__ x0p = src + (size_t)(row0 + rg     ) * DQ;
    const float* __restrict__ x1p = src + (size_t)(row0 + rg +  4) * DQ;
    const float* __restrict__ x2p = src + (size_t)(row0 + rg +  8) * DQ;
    const float* __restrict__ x3p = src + (size_t)(row0 + rg + 12) * DQ;

    float acc0 = 0.f, acc1 = 0.f, acc2 = 0.f, acc3 = 0.f;
#pragma unroll 4
    for (int d4 = 0; d4 < DQ / 4; ++d4) {
        const float4 w  = w4[d4 * H + h];
        const float4 x0 = *(const float4*)(x0p + d4 * 4);
        const float4 x1 = *(const float4*)(x1p + d4 * 4);
        const float4 x2 = *(const float4*)(x2p + d4 * 4);
        const float4 x3 = *(const float4*)(x3p + d4 * 4);
        acc0 = fmaf(w.x, x0.x, acc0); acc0 = fmaf(w.y, x0.y, acc0);
        acc0 = fmaf(w.z, x0.z, acc0); acc0 = fmaf(w.w, x0.w, acc0);
        acc1 = fmaf(w.x, x1.x, acc1); acc1 = fmaf(w.y, x1.y, acc1);
        acc1 = fmaf(w.z, x1.z, acc1); acc1 = fmaf(w.w, x1.w, acc1);
        acc2 = fmaf(w.x, x2.x, acc2); acc2 = fmaf(w.y, x2.y, acc2);
        acc2 = fmaf(w.z, x2.z, acc2); acc2 = fmaf(w.w, x2.w, acc2);
        acc3 = fmaf(w.x, x3.x, acc3); acc3 = fmaf(w.y, x3.y, acc3);
        acc3 = fmaf(w.z, x3.z, acc3); acc3 = fmaf(w.w, x3.w, acc3);
    }

    const float bias = (is_q ? bq : bc)[h];
    if (is_q) {
        Eq[(size_t)(row0 + rg     ) * H + h] = __expf(2.f * (acc0 + bias));
        Eq[(size_t)(row0 + rg +  4) * H + h] = __expf(2.f * (acc1 + bias));
        Eq[(size_t)(row0 + rg +  8) * H + h] = __expf(2.f * (acc2 + bias));
        Eq[(size_t)(row0 + rg + 12) * H + h] = __expf(2.f * (acc3 + bias));
    } else {
        const int h4 = h >> 2, hl = h & 3;
        float e[4] = {__expf(4.f * (acc0 + bias)), __expf(4.f * (acc1 + bias)),
                      __expf(4.f * (acc2 + bias)), __expf(4.f * (acc3 + bias))};
#pragma unroll
        for (int i = 0; i < 4; ++i) {
            const int rc = row0 + rg + i * 4;
            const int bb = rc >> 9, kk = rc & 511;
            EcT4[(((size_t)(bb * 32 + h4) * LK + kk) << 2) + hl] = e[i];
        }
    }
}

// ---------------------------------------------------------------------------
// Attention: 512 threads (8 waves), 4 q-rows/block, grid = 512 (2 blocks/CU).
// Score: thread t owns k=t; EcT4 one float4/iter; Eq/Wv LDS broadcast;
// paired reciprocals. Softmax: waves 0-3 own rows 0-3. Epilogue: wave w owns
// k-slice [64w,64w+64), float4 ctx loads, LDS partial reduce over 8 slices.
// ---------------------------------------------------------------------------
__global__ __launch_bounds__(512, 4) void ca_attn_kernel(
    const float* __restrict__ Eq, const float* __restrict__ EcT4,
    const float* __restrict__ context, const float* __restrict__ Wv,
    float* __restrict__ out)
{
    __shared__ float sc[4][LK];        // 8 KB: scores, then unnormalized p
    __shared__ float part[8][4][DC];   // 32 KB: epilogue partials
    __shared__ float eqs[4][H];        // 2 KB
    __shared__ float wv[H];            // 0.5 KB
    __shared__ float inv[4];

    const int t = threadIdx.x;
    const int bq0 = blockIdx.x * 4;
    const int b = bq0 / LQ;

    if (t < H) {
        wv[t] = Wv[t];
#pragma unroll
        for (int g = 0; g < 4; ++g) eqs[g][t] = Eq[(size_t)(bq0 + g) * H + t];
    }
    __syncthreads();

    const float4* __restrict__ ecb = (const float4*)EcT4 + (size_t)b * 32 * LK;

    // ---- scores: s[g][k=t] ~ -2 * sum_h Wv[h] / (Eq[g][h]*Ec[h][k] + 1)
    float a[4] = {0.f, 0.f, 0.f, 0.f};
#pragma unroll 4
    for (int h4 = 0; h4 < H / 4; ++h4) {
        const float4 e = ecb[h4 * LK + t];
        const float4 w = *(const float4*)&wv[h4 * 4];
#pragma unroll
        for (int g = 0; g < 4; ++g) {
            const float4 q = *(const float4*)&eqs[g][h4 * 4];
            const float A = fmaf(q.x, e.x, 1.f);
            const float Bv = fmaf(q.y, e.y, 1.f);
            const float C = fmaf(q.z, e.z, 1.f);
            const float D = fmaf(q.w, e.w, 1.f);
            float n1 = w.x * Bv; n1 = fmaf(w.y, A, n1);
            float n2 = w.z * D;  n2 = fmaf(w.w, C, n2);
            const float r1 = __builtin_amdgcn_rcpf(A * Bv);
            const float r2 = __builtin_amdgcn_rcpf(C * D);
            a[g] = fmaf(n1, r1, a[g]);
            a[g] = fmaf(n2, r2, a[g]);
        }
    }
#pragma unroll
    for (int g = 0; g < 4; ++g) sc[g][t] = -2.f * a[g];
    __syncthreads();

    // ---- softmax: wave w (<4) owns row w; store raw exp, inv = 1/sum
    {
        const int w_id = t >> 6;
        const int lane = t & 63;
        if (w_id < 4) {
            float v[8];
#pragma unroll
            for (int i = 0; i < 8; ++i) v[i] = sc[w_id][lane + 64 * i];
            float m = v[0];
#pragma unroll
            for (int i = 1; i < 8; ++i) m = fmaxf(m, v[i]);
#pragma unroll
            for (int off = 32; off > 0; off >>= 1) m = fmaxf(m, __shfl_xor(m, off));
            float s = 0.f;
#pragma unroll
            for (int i = 0; i < 8; ++i) { v[i] = __expf(v[i] - m); s += v[i]; }
#pragma unroll
            for (int off = 32; off > 0; off >>= 1) s += __shfl_xor(s, off);
#pragma unroll
            for (int i = 0; i < 8; ++i) sc[w_id][lane + 64 * i] = v[i];
            if (lane == 0) inv[w_id] = 1.f / s;
        }
    }
    __syncthreads();

    // ---- epilogue: part[w][g][d] = sum_{k in slice w} p[g][k]*ctx[k][d]
    {
        const int kh = t >> 6;            // wave id = k-slice
        const int d4 = (t & 63) * 4;
        const float* __restrict__ ctx = context + (size_t)b * LK * DC + d4;
        float4 o[4];
#pragma unroll
        for (int g = 0; g < 4; ++g) o[g] = make_float4(0.f, 0.f, 0.f, 0.f);
#pragma unroll 2
        for (int j = 0; j < 16; ++j) {    // 4 k per iter
            const int k = kh * 64 + j * 4;
            float4 p[4];
#pragma unroll
            for (int g = 0; g < 4; ++g) p[g] = *(const float4*)&sc[g][k];
#pragma unroll
            for (int c = 0; c < 4; ++c) {
                const float4 cv = *(const float4*)(ctx + (size_t)(k + c) * DC);
                const float pc[4] = {p[0].x, p[1].x, p[2].x, p[3].x};
                const float pd[4] = {p[0].y, p[1].y, p[2].y, p[3].y};
                const float pe[4] = {p[0].z, p[1].z, p[2].z, p[3].z};
                const float pf[4] = {p[0].w, p[1].w, p[2].w, p[3].w};
                const float* sel = (c == 0) ? pc : (c == 1) ? pd : (c == 2) ? pe : pf;
#pragma unroll
                for (int g = 0; g < 4; ++g) {
                    o[g].x = fmaf(sel[g], cv.x, o[g].x);
                    o[g].y = fmaf(sel[g], cv.y, o[g].y);
                    o[g].z = fmaf(sel[g], cv.z, o[g].z);
                    o[g].w = fmaf(sel[g], cv.w, o[g].w);
                }
            }
        }
#pragma unroll
        for (int g = 0; g < 4; ++g)
            *(float4*)&part[kh][g][d4] = o[g];
    }
    __syncthreads();

    // ---- combine the 8 k-slices, scale by 1/sum, store
    if (t < 256) {
#pragma unroll
        for (int g = 0; g < 4; ++g) {
            float s = 0.f;
#pragma unroll
            for (int kh = 0; kh < 8; ++kh) s += part[kh][g][t];
            out[(size_t)(bq0 + g) * DC + t] = s * inv[g];
        }
    }
}

extern "C" void kernel_launch(void* const* d_in, const int* in_sizes, int n_in,
                              void* d_out, int out_size, void* d_ws, size_t ws_size,
                              hipStream_t stream) {
    const float* query   = (const float*)d_in[0];
    const float* context = (const float*)d_in[1];
    const float* Wq = (const float*)d_in[2];
    const float* bq = (const float*)d_in[3];
    const float* Wc = (const float*)d_in[4];
    const float* bc = (const float*)d_in[5];
    const float* Wv = (const float*)d_in[6];
    const float* bv = (const float*)d_in[7];  // dropped: softmax shift-invariant
    (void)bv;
    float* out = (float*)d_out;

    float* Eq   = (float*)d_ws;                     // 262144 floats
    float* EcT4 = Eq  + (size_t)B * LQ * H;         // 262144 floats
    float* WqT4 = EcT4 + (size_t)B * H * LK;        // 32768 floats
    float* WcT4 = WqT4 + (size_t)H * DQ;            // 32768 floats

    ca_wt_kernel<<<256, 256, 0, stream>>>(Wq, Wc, WqT4, WcT4);
    ca_proj_kernel<<<B * (LQ + LK) / 16, 512, 0, stream>>>(
        query, context, WqT4, WcT4, bq, bc, Eq, EcT4);
    ca_attn_kernel<<<B * LQ / 4, 512, 0, stream>>>(Eq, EcT4, context, Wv, out);
}